// Round 1
// baseline (181.260 us; speedup 1.0000x reference)
//
#include <hip/hip_runtime.h>

#define FFT_N   4096
#define NT      256
// skewed LDS index: +1 float2 pad every 16 to break power-of-2 bank strides
#define SKEW(i) ((i) + ((i) >> 4))

__device__ __forceinline__ float2 cmul(float2 a, float2 b) {
    return make_float2(a.x * b.x - a.y * b.y, a.x * b.y + a.y * b.x);
}

__global__ __launch_bounds__(NT) void circconv4096_kernel(
    const float* __restrict__ A, const float* __restrict__ Bv,
    float* __restrict__ O)
{
    __shared__ float2 Z[FFT_N + (FFT_N >> 4)];
    const int tid = threadIdx.x;
    const size_t row = blockIdx.x;
    const float* a = A + row * FFT_N;
    const float* b = Bv + row * FFT_N;
    float* o = O + row * FFT_N;

    // ---- load: z = a + i*b, float4-vectorized global reads ----
#pragma unroll
    for (int k = 0; k < 4; ++k) {
        int slot = tid + k * NT;          // 1024 slots of 4 elements
        int i0 = slot * 4;
        float4 av = *reinterpret_cast<const float4*>(a + i0);
        float4 bv = *reinterpret_cast<const float4*>(b + i0);
        Z[SKEW(i0 + 0)] = make_float2(av.x, bv.x);
        Z[SKEW(i0 + 1)] = make_float2(av.y, bv.y);
        Z[SKEW(i0 + 2)] = make_float2(av.z, bv.z);
        Z[SKEW(i0 + 3)] = make_float2(av.w, bv.w);
    }
    __syncthreads();

    // ---- forward DIF radix-4 (output digit-reversed; that's fine) ----
#pragma unroll
    for (int s = 0; s < 6; ++s) {
        const int Mlog = 10 - 2 * s;          // M = L/4, L = 4096 >> 2s
        const int M = 1 << Mlog;
        const float step = -6.28318530717958647692f / (float)(4 << Mlog);
#pragma unroll
        for (int k = 0; k < 4; ++k) {
            int t = tid + (k << 8);           // 1024 butterflies/stage
            int j = t & (M - 1);
            int base = ((t >> Mlog) << (Mlog + 2)) + j;
            float2 x0 = Z[SKEW(base)];
            float2 x1 = Z[SKEW(base + M)];
            float2 x2 = Z[SKEW(base + 2 * M)];
            float2 x3 = Z[SKEW(base + 3 * M)];
            float2 a0 = make_float2(x0.x + x2.x, x0.y + x2.y);
            float2 a1 = make_float2(x0.x - x2.x, x0.y - x2.y);
            float2 a2 = make_float2(x1.x + x3.x, x1.y + x3.y);
            float2 a3 = make_float2(x1.x - x3.x, x1.y - x3.y);
            float2 b0 = make_float2(a0.x + a2.x, a0.y + a2.y);
            float2 b2 = make_float2(a0.x - a2.x, a0.y - a2.y);
            float2 b1 = make_float2(a1.x + a3.y, a1.y - a3.x);   // a1 - i*a3
            float2 b3 = make_float2(a1.x - a3.y, a1.y + a3.x);   // a1 + i*a3
            float ang = step * (float)j;
            float sn, cs;
            __sincosf(ang, &sn, &cs);
            float2 w1 = make_float2(cs, sn);
            float2 w2 = cmul(w1, w1);
            float2 w3 = cmul(w2, w1);
            Z[SKEW(base)]         = b0;
            Z[SKEW(base + M)]     = cmul(b1, w1);
            Z[SKEW(base + 2 * M)] = cmul(b2, w2);
            Z[SKEW(base + 3 * M)] = cmul(b3, w3);
        }
        __syncthreads();
    }

    // ---- pointwise square: IFFT(Z^2) = (a*a - b*b) + 2i*(a (*) b) ----
#pragma unroll
    for (int k = 0; k < 16; ++k) {
        int idx = SKEW(tid + k * NT);
        float2 z = Z[idx];
        Z[idx] = make_float2(z.x * z.x - z.y * z.y, 2.0f * z.x * z.y);
    }
    __syncthreads();

    // ---- inverse DIT radix-4 (consumes digit-reversed, natural output) ----
#pragma unroll
    for (int s = 0; s < 6; ++s) {
        const int Mlog = 2 * s;               // L = 4 << 2s
        const int M = 1 << Mlog;
        const float step = 6.28318530717958647692f / (float)(4 << Mlog);
#pragma unroll
        for (int k = 0; k < 4; ++k) {
            int t = tid + (k << 8);
            int j = t & (M - 1);
            int base = ((t >> Mlog) << (Mlog + 2)) + j;
            float2 y0 = Z[SKEW(base)];
            float2 y1 = Z[SKEW(base + M)];
            float2 y2 = Z[SKEW(base + 2 * M)];
            float2 y3 = Z[SKEW(base + 3 * M)];
            float ang = step * (float)j;
            float sn, cs;
            __sincosf(ang, &sn, &cs);
            float2 w1 = make_float2(cs, sn);    // conj of forward twiddle
            float2 w2 = cmul(w1, w1);
            float2 w3 = cmul(w2, w1);
            float2 c0 = y0;
            float2 c1 = cmul(y1, w1);
            float2 c2 = cmul(y2, w2);
            float2 c3 = cmul(y3, w3);
            float2 d0 = make_float2(c0.x + c2.x, c0.y + c2.y);
            float2 d1 = make_float2(c0.x - c2.x, c0.y - c2.y);
            float2 d2 = make_float2(c1.x + c3.x, c1.y + c3.y);
            float2 d3 = make_float2(c1.x - c3.x, c1.y - c3.y);
            Z[SKEW(base)]         = make_float2(d0.x + d2.x, d0.y + d2.y);
            Z[SKEW(base + 2 * M)] = make_float2(d0.x - d2.x, d0.y - d2.y);
            Z[SKEW(base + M)]     = make_float2(d1.x - d3.y, d1.y + d3.x); // d1 + i*d3
            Z[SKEW(base + 3 * M)] = make_float2(d1.x + d3.y, d1.y - d3.x); // d1 - i*d3
        }
        __syncthreads();
    }

    // ---- store: out = imag(Z) / (2N)  (inverse stages are unnormalized: xN) ----
    const float scale = 1.0f / (2.0f * (float)FFT_N);
#pragma unroll
    for (int k = 0; k < 4; ++k) {
        int slot = tid + k * NT;
        int i0 = slot * 4;
        float4 ov;
        ov.x = Z[SKEW(i0 + 0)].y * scale;
        ov.y = Z[SKEW(i0 + 1)].y * scale;
        ov.z = Z[SKEW(i0 + 2)].y * scale;
        ov.w = Z[SKEW(i0 + 3)].y * scale;
        *reinterpret_cast<float4*>(o + i0) = ov;
    }
}

extern "C" void kernel_launch(void* const* d_in, const int* in_sizes, int n_in,
                              void* d_out, int out_size, void* d_ws, size_t ws_size,
                              hipStream_t stream) {
    const float* a = (const float*)d_in[0];
    const float* b = (const float*)d_in[1];
    float* out = (float*)d_out;
    const int B = in_sizes[0] / FFT_N;   // 8192 rows
    circconv4096_kernel<<<B, NT, 0, stream>>>(a, b, out);
}

// Round 2
// 142.888 us; speedup vs baseline: 1.2685x; 1.2685x over previous
//
#include <hip/hip_runtime.h>

#define FFT_N 4096
#define NT    256
// skew: stride-16 blocks rotate banks by 2, stride-256 blocks rotate by 4
#define SK(i) ((i) + ((i) >> 4) + 2 * ((i) >> 8))

__device__ __forceinline__ float2 cadd(float2 a, float2 b) { return make_float2(a.x + b.x, a.y + b.y); }
__device__ __forceinline__ float2 csub(float2 a, float2 b) { return make_float2(a.x - b.x, a.y - b.y); }
__device__ __forceinline__ float2 cmul(float2 a, float2 b) {
    return make_float2(a.x * b.x - a.y * b.y, a.x * b.y + a.y * b.x);
}
__device__ __forceinline__ float2 cmulc(float2 a, float re, float im) {
    return make_float2(a.x * re - a.y * im, a.x * im + a.y * re);
}

// In-register 16-point DFT, natural order in and out.
// SGN = -1: y[k] = sum_n x[n] e^{-2pi i nk/16};  SGN = +1: conjugate (unnormalized).
template <int SGN>
__device__ __forceinline__ void dft16(float2* x) {
    const float S = (float)SGN;
    const float C1 = 0.923879532511286756f;   // cos(pi/8)
    const float S1 = 0.382683432365089772f;   // sin(pi/8)
    const float R2 = 0.707106781186547524f;   // sqrt(2)/2
    float2 B[16];  // B[n0*4 + r]
#pragma unroll
    for (int n0 = 0; n0 < 4; ++n0) {
        float2 x0 = x[n0], x1 = x[n0 + 4], x2 = x[n0 + 8], x3 = x[n0 + 12];
        float2 t0 = cadd(x0, x2);
        float2 t1 = csub(x0, x2);
        float2 t2 = cadd(x1, x3);
        float2 t3 = csub(x1, x3);
        float2 it3 = make_float2(-S * t3.y, S * t3.x);  // SGN * i * t3
        B[n0 * 4 + 0] = cadd(t0, t2);
        B[n0 * 4 + 2] = csub(t0, t2);
        B[n0 * 4 + 1] = cadd(t1, it3);
        B[n0 * 4 + 3] = csub(t1, it3);
    }
    // twiddles W16^{SGN * n0 * r} for n0,r in 1..3 (constants)
    B[1 * 4 + 1] = cmulc(B[1 * 4 + 1], C1, S * S1);    // w1
    B[1 * 4 + 2] = cmulc(B[1 * 4 + 2], R2, S * R2);    // w2
    B[1 * 4 + 3] = cmulc(B[1 * 4 + 3], S1, S * C1);    // w3
    B[2 * 4 + 1] = cmulc(B[2 * 4 + 1], R2, S * R2);    // w2
    {   // w4 = SGN*i
        float2 v = B[2 * 4 + 2];
        B[2 * 4 + 2] = make_float2(-S * v.y, S * v.x);
    }
    B[2 * 4 + 3] = cmulc(B[2 * 4 + 3], -R2, S * R2);   // w6
    B[3 * 4 + 1] = cmulc(B[3 * 4 + 1], S1, S * C1);    // w3
    B[3 * 4 + 2] = cmulc(B[3 * 4 + 2], -R2, S * R2);   // w6
    B[3 * 4 + 3] = cmulc(B[3 * 4 + 3], -C1, -S * S1);  // w9
    // second radix-4 layer over n0, output y[r + 4s]
#pragma unroll
    for (int r = 0; r < 4; ++r) {
        float2 b0 = B[0 * 4 + r], b1 = B[1 * 4 + r], b2 = B[2 * 4 + r], b3 = B[3 * 4 + r];
        float2 t0 = cadd(b0, b2);
        float2 t1 = csub(b0, b2);
        float2 t2 = cadd(b1, b3);
        float2 t3 = csub(b1, b3);
        float2 it3 = make_float2(-S * t3.y, S * t3.x);
        x[r + 0]  = cadd(t0, t2);
        x[r + 8]  = csub(t0, t2);
        x[r + 4]  = cadd(t1, it3);
        x[r + 12] = csub(t1, it3);
    }
}

__global__ __launch_bounds__(NT, 4) void circconv4096_kernel(
    const float* __restrict__ A, const float* __restrict__ Bv,
    float* __restrict__ O)
{
    __shared__ float2 Z[4381];  // SK(4095)+1
    const int t = threadIdx.x;
    const size_t row = blockIdx.x;
    const float* a = A + row * FFT_N;
    const float* b = Bv + row * FFT_N;
    float* o = O + row * FFT_N;

    float2 x[16];

    // ---- step 1: global load (stride-256, coalesced) + fwd radix-16 stage M=256 ----
#pragma unroll
    for (int q = 0; q < 16; ++q) {
        int g = t + NT * q;
        x[q] = make_float2(a[g], b[g]);  // z = a + i*b
    }
    dft16<-1>(x);
    {   // twiddle W4096^{t*r}
        float sn, cs;
        __sincosf(-6.28318530717958647692f * (float)t / 4096.0f, &sn, &cs);
        float2 w1 = make_float2(cs, sn), w = w1;
#pragma unroll
        for (int r = 1; r < 16; ++r) { x[r] = cmul(x[r], w); w = cmul(w, w1); }
    }
#pragma unroll
    for (int r = 0; r < 16; ++r) Z[SK(t + NT * r)] = x[r];
    __syncthreads();

    // ---- step 2: fwd radix-16 stage M=16 ----
    {
        const int blk = t >> 4, j = t & 15;
        const int base = blk * 256 + j;
#pragma unroll
        for (int q = 0; q < 16; ++q) x[q] = Z[SK(base + 16 * q)];
        dft16<-1>(x);
        float sn, cs;
        __sincosf(-6.28318530717958647692f * (float)j / 256.0f, &sn, &cs);
        float2 w1 = make_float2(cs, sn), w = w1;
#pragma unroll
        for (int r = 1; r < 16; ++r) { x[r] = cmul(x[r], w); w = cmul(w, w1); }
#pragma unroll
        for (int r = 0; r < 16; ++r) Z[SK(base + 16 * r)] = x[r];
    }
    __syncthreads();

    // ---- step 3: fwd M=1 + pointwise square + inv M=1 (all in registers) ----
    {
        const int base = t * 16;
#pragma unroll
        for (int q = 0; q < 16; ++q) x[q] = Z[SK(base + q)];
        dft16<-1>(x);
#pragma unroll
        for (int r = 0; r < 16; ++r) {
            float2 z = x[r];
            // IFFT(Z^2) = (a*a - b*b) + 2i*(a (*) b)
            x[r] = make_float2(z.x * z.x - z.y * z.y, 2.0f * z.x * z.y);
        }
        dft16<1>(x);
#pragma unroll
        for (int q = 0; q < 16; ++q) Z[SK(base + q)] = x[q];
    }
    __syncthreads();

    // ---- step 4: inv radix-16 stage M=16 (conj twiddle BEFORE inverse dft) ----
    {
        const int blk = t >> 4, j = t & 15;
        const int base = blk * 256 + j;
#pragma unroll
        for (int r = 0; r < 16; ++r) x[r] = Z[SK(base + 16 * r)];
        float sn, cs;
        __sincosf(6.28318530717958647692f * (float)j / 256.0f, &sn, &cs);
        float2 w1 = make_float2(cs, sn), w = w1;
#pragma unroll
        for (int r = 1; r < 16; ++r) { x[r] = cmul(x[r], w); w = cmul(w, w1); }
        dft16<1>(x);
#pragma unroll
        for (int q = 0; q < 16; ++q) Z[SK(base + 16 * q)] = x[q];
    }
    __syncthreads();

    // ---- step 5: inv radix-16 stage M=256 + store (coalesced) ----
    {
#pragma unroll
        for (int r = 0; r < 16; ++r) x[r] = Z[SK(t + NT * r)];
        float sn, cs;
        __sincosf(6.28318530717958647692f * (float)t / 4096.0f, &sn, &cs);
        float2 w1 = make_float2(cs, sn), w = w1;
#pragma unroll
        for (int r = 1; r < 16; ++r) { x[r] = cmul(x[r], w); w = cmul(w, w1); }
        dft16<1>(x);
        // three unnormalized inverse dft16s give x4096; imag trick gives /2
        const float scale = 1.0f / 8192.0f;
#pragma unroll
        for (int q = 0; q < 16; ++q) o[t + NT * q] = x[q].y * scale;
    }
}

extern "C" void kernel_launch(void* const* d_in, const int* in_sizes, int n_in,
                              void* d_out, int out_size, void* d_ws, size_t ws_size,
                              hipStream_t stream) {
    const float* a = (const float*)d_in[0];
    const float* b = (const float*)d_in[1];
    float* out = (float*)d_out;
    const int B = in_sizes[0] / FFT_N;  // 8192 rows
    circconv4096_kernel<<<B, NT, 0, stream>>>(a, b, out);
}